// Round 2
// baseline (496.874 us; speedup 1.0000x reference)
//
#include <hip/hip_runtime.h>

// SNN with "swapped outputs" bug: stored state = spike (binary), forwarded
// value = membrane. reset = (spk_prev > 1) == 0 always, so mem = cur + 0.9*spk_prev.
// With constant input current every layer's spike pattern fixates:
//   mem0 const for t>=1, mem1 const for t>=2, mem2 (output) const for t>=3.
// GEMM0 (256x2048,K=1024) once; GEMM1 over {mem0(0), mem0(inf)} (M=512,K=2048);
// GEMM2 over {mem1(0), mem1(1), mem1(inf)} (M=768,K=2048); broadcast t>=3.
// f64 accumulation keeps spike-threshold decisions aligned with the reference
// (empirically verified passing in round 1). This round: pipelined f64 GEMM
// (register prefetch, ds_read_b128 fragments, even grid fill) targeting the
// 78.6 TF f64 vector roofline (~110us of GEMM work).

#define KT 32

template <int RPT>  // rows per thread; tile = (16*RPT) x 64, 256 threads
__global__ __launch_bounds__(256, 1) void gemm_f64(
    const float* __restrict__ A,    // [M,K] row-major
    const float* __restrict__ W,    // [N,K] row-major (C = A @ W^T + bias)
    const float* __restrict__ bias, // [N]
    float* __restrict__ C,          // [M,N]
    int N, int K)
{
    constexpr int TM = 16 * RPT;
    constexpr int TN = 64;
    constexpr int LA = (TM * KT / 4 + 255) / 256;  // float4 loads/thread for A
    constexpr int LW = (TN * KT / 4) / 256;        // = 2
    constexpr bool GUARD_A = (TM * KT / 4) % 256 != 0;

    __shared__ double As[KT][TM];
    __shared__ double Ws[KT][TN];

    const int tid  = threadIdx.x;
    const int tx   = tid & 15;   // 4 cols each
    const int ty   = tid >> 4;   // RPT rows each
    const int row0 = blockIdx.y * TM;
    const int col0 = blockIdx.x * TN;

    float4 ra[LA], rw[LW];

    auto loadA = [&](int k0) {
#pragma unroll
        for (int i = 0; i < LA; ++i) {
            int idx = i * 256 + tid;
            if (!GUARD_A || idx < TM * (KT / 4)) {
                int r = idx >> 3, c = (idx & 7) << 2;
                ra[i] = *reinterpret_cast<const float4*>(
                    A + (size_t)(row0 + r) * K + k0 + c);
            }
        }
    };
    auto loadW = [&](int k0) {
#pragma unroll
        for (int i = 0; i < LW; ++i) {
            int idx = i * 256 + tid;
            int r = idx >> 3, c = (idx & 7) << 2;
            rw[i] = *reinterpret_cast<const float4*>(
                W + (size_t)(col0 + r) * K + k0 + c);
        }
    };
    auto storeA = [&]() {
#pragma unroll
        for (int i = 0; i < LA; ++i) {
            int idx = i * 256 + tid;
            if (!GUARD_A || idx < TM * (KT / 4)) {
                int r = idx >> 3, c = (idx & 7) << 2;
                As[c + 0][r] = (double)ra[i].x;
                As[c + 1][r] = (double)ra[i].y;
                As[c + 2][r] = (double)ra[i].z;
                As[c + 3][r] = (double)ra[i].w;
            }
        }
    };
    auto storeW = [&]() {
#pragma unroll
        for (int i = 0; i < LW; ++i) {
            int idx = i * 256 + tid;
            int r = idx >> 3, c = (idx & 7) << 2;
            Ws[c + 0][r] = (double)rw[i].x;
            Ws[c + 1][r] = (double)rw[i].y;
            Ws[c + 2][r] = (double)rw[i].z;
            Ws[c + 3][r] = (double)rw[i].w;
        }
    };

    double acc[RPT][4] = {};
    const int NT = K / KT;

    loadA(0);
    loadW(0);

    for (int kt = 0; kt < NT; ++kt) {
        __syncthreads();      // previous compute done; LDS reusable
        storeA();
        storeW();
        __syncthreads();      // LDS tile ready
        if (kt + 1 < NT) {    // prefetch next tile, overlaps compute below
            loadA((kt + 1) * KT);
            loadW((kt + 1) * KT);
        }
#pragma unroll
        for (int kk = 0; kk < KT; ++kk) {
            double a[RPT], w[4];
#pragma unroll
            for (int r = 0; r < RPT; ++r) a[r] = As[kk][ty * RPT + r];
#pragma unroll
            for (int j = 0; j < 4; ++j)  w[j] = Ws[kk][tx * 4 + j];
#pragma unroll
            for (int r = 0; r < RPT; ++r)
#pragma unroll
                for (int j = 0; j < 4; ++j)
                    acc[r][j] = fma(a[r], w[j], acc[r][j]);
        }
    }

    const float4 bv = *reinterpret_cast<const float4*>(bias + col0 + tx * 4);
#pragma unroll
    for (int r = 0; r < RPT; ++r) {
        float4 o;
        o.x = (float)(acc[r][0] + (double)bv.x);
        o.y = (float)(acc[r][1] + (double)bv.y);
        o.z = (float)(acc[r][2] + (double)bv.z);
        o.w = (float)(acc[r][3] + (double)bv.w);
        *reinterpret_cast<float4*>(
            &C[(size_t)(row0 + ty * RPT + r) * N + col0 + tx * 4]) = o;
    }
}

// mem0(inf) = cur0 + 0.9*[cur0 > 1]; cur0 in lo half (n4 float4s), write hi half.
__global__ __launch_bounds__(256) void lif0_kernel(float4* __restrict__ a1, int n4)
{
    int i = blockIdx.x * 256 + threadIdx.x;
    if (i < n4) {
        float4 c = a1[i], o;
        o.x = c.x + ((c.x > 1.0f) ? 0.9f : 0.0f);
        o.y = c.y + ((c.y > 1.0f) ? 0.9f : 0.0f);
        o.z = c.z + ((c.z > 1.0f) ? 0.9f : 0.0f);
        o.w = c.w + ((c.w > 1.0f) ? 0.9f : 0.0f);
        a1[n4 + i] = o;
    }
}

// From cur1(0), cur1(inf) build mem1(0), mem1(1), mem1(inf).
__global__ __launch_bounds__(256) void lif1_kernel(const float4* __restrict__ c1,
                                                   float4* __restrict__ a2, int n4)
{
    int i = blockIdx.x * 256 + threadIdx.x;
    if (i < n4) {
        float4 c0 = c1[i], ci = c1[n4 + i];
        float4 m0 = c0, m1, mi;
        m1.x = ci.x + ((m0.x > 1.0f) ? 0.9f : 0.0f);
        m1.y = ci.y + ((m0.y > 1.0f) ? 0.9f : 0.0f);
        m1.z = ci.z + ((m0.z > 1.0f) ? 0.9f : 0.0f);
        m1.w = ci.w + ((m0.w > 1.0f) ? 0.9f : 0.0f);
        mi.x = ci.x + ((m1.x > 1.0f) ? 0.9f : 0.0f);
        mi.y = ci.y + ((m1.y > 1.0f) ? 0.9f : 0.0f);
        mi.z = ci.z + ((m1.z > 1.0f) ? 0.9f : 0.0f);
        mi.w = ci.w + ((m1.w > 1.0f) ? 0.9f : 0.0f);
        a2[i] = m0;
        a2[n4 + i] = m1;
        a2[2 * n4 + i] = mi;
    }
}

// Final layer + output broadcast. n4 = 256*1024/4.
__global__ __launch_bounds__(256) void lif2_kernel(const float4* __restrict__ c2,
                                                   float4* __restrict__ out, int n4)
{
    int i = blockIdx.x * 256 + threadIdx.x;
    if (i < n4) {
        float4 c0 = c2[i], c1 = c2[n4 + i], ci = c2[2 * n4 + i];
        float4 m0 = c0, m1, m2, m3;
        m1.x = c1.x + ((m0.x > 1.0f) ? 0.9f : 0.0f);
        m1.y = c1.y + ((m0.y > 1.0f) ? 0.9f : 0.0f);
        m1.z = c1.z + ((m0.z > 1.0f) ? 0.9f : 0.0f);
        m1.w = c1.w + ((m0.w > 1.0f) ? 0.9f : 0.0f);
        m2.x = ci.x + ((m1.x > 1.0f) ? 0.9f : 0.0f);
        m2.y = ci.y + ((m1.y > 1.0f) ? 0.9f : 0.0f);
        m2.z = ci.z + ((m1.z > 1.0f) ? 0.9f : 0.0f);
        m2.w = ci.w + ((m1.w > 1.0f) ? 0.9f : 0.0f);
        m3.x = ci.x + ((m2.x > 1.0f) ? 0.9f : 0.0f);
        m3.y = ci.y + ((m2.y > 1.0f) ? 0.9f : 0.0f);
        m3.z = ci.z + ((m2.z > 1.0f) ? 0.9f : 0.0f);
        m3.w = ci.w + ((m2.w > 1.0f) ? 0.9f : 0.0f);
        out[i] = m0;
        out[n4 + i] = m1;
        out[2 * n4 + i] = m2;
        for (int t = 3; t < 100; ++t)
            out[(size_t)t * n4 + i] = m3;
    }
}

extern "C" void kernel_launch(void* const* d_in, const int* in_sizes, int n_in,
                              void* d_out, int out_size, void* d_ws, size_t ws_size,
                              hipStream_t stream)
{
    const float* x  = (const float*)d_in[0];  // [256,1024]
    const float* W0 = (const float*)d_in[1];  // [2048,1024]
    const float* b0 = (const float*)d_in[2];  // [2048]
    const float* W1 = (const float*)d_in[3];  // [2048,2048]
    const float* b1 = (const float*)d_in[4];  // [2048]
    const float* W2 = (const float*)d_in[5];  // [1024,2048]
    const float* b2 = (const float*)d_in[6];  // [1024]
    float* out = (float*)d_out;
    float* ws  = (float*)d_ws;

    const int B = 256, H = 2048, DOUT = 1024, DIN = 1024;
    const int nBH4 = B * H / 4;      // 131072 float4
    const int nBO4 = B * DOUT / 4;   // 65536 float4

    // ws layout (floats): A1 [512,2048] @0 ; C1 [512,2048] @1048576 ;
    // A2 [768,2048] @2097152 ; C2 [768,1024] reuses A1's slot (A1 dead by then).
    float* A1 = ws;
    float* C1 = ws + 1048576;
    float* A2 = ws + 2097152;
    float* C2 = ws;

    dim3 blk(256);

    // GEMM0: cur0 = x @ W0^T + b0 -> rows 0..255 of A1. TM=32 -> grid 32x8=256.
    gemm_f64<2><<<dim3(H / 64, B / 32), blk, 0, stream>>>(x, W0, b0, A1, H, DIN);
    // mem0(inf) -> rows 256..511 of A1
    lif0_kernel<<<dim3(nBH4 / 256), blk, 0, stream>>>((float4*)A1, nBH4);
    // GEMM1: [cur1(0); cur1(inf)] = [mem0(0); mem0(inf)] @ W1^T + b1. TM=64 -> 32x8=256.
    gemm_f64<4><<<dim3(H / 64, (2 * B) / 64), blk, 0, stream>>>(A1, W1, b1, C1, H, H);
    // mem1(0), mem1(1), mem1(inf)
    lif1_kernel<<<dim3(nBH4 / 256), blk, 0, stream>>>((const float4*)C1, (float4*)A2, nBH4);
    // GEMM2: 3 currents for layer 2. TM=48 -> grid 16x16=256 (even CU fill).
    gemm_f64<3><<<dim3(DOUT / 64, (3 * B) / 48), blk, 0, stream>>>(A2, W2, b2, C2, DOUT, H);
    // layer-2 LIF + output broadcast (t>=3 fixed point)
    lif2_kernel<<<dim3(nBO4 / 256), blk, 0, stream>>>((const float4*)C2, (float4*)out, nBO4);
}

// Round 4
// 382.913 us; speedup vs baseline: 1.2976x; 1.2976x over previous
//
#include <hip/hip_runtime.h>

// SNN with "swapped outputs" bug: stored state = spike (binary), forwarded
// value = membrane. reset = (spk_prev > 1) == 0 always, so mem = cur + 0.9*spk_prev.
// With constant input current every layer's spike pattern fixates:
//   mem0 const for t>=1, mem1 const for t>=2, mem2 (output) const for t>=3.
// GEMM0 (256x2048,K=1024) once; GEMM1 over {mem0(0), mem0(inf)} (M=512,K=2048);
// GEMM2 over {mem1(0), mem1(1), mem1(inf)} (M=768,K=2048); broadcast t>=3.
//
// Round-2 lesson: vector-f64 4x4 register tiles are LDS-pipe-bound. Round-3
// lesson: v_mfma_f64_16x16x4_f64's C/D layout differs from the bf16 16x16
// family -> wrong-row writes. Round 4: probe the C/D layout at runtime with
// two known-operand MFMAs (A=row-index, B=1 -> D[m][n]=4m; A=1, B=col-index
// -> D[m][n]=4n), then write the epilogue through the probed (row,col) map.
// f64 accumulation keeps spike-threshold decisions aligned with the reference.

typedef double f64x4 __attribute__((ext_vector_type(4)));

#define KT 32
#define LDSS (KT + 4)   // 36-word row stride: frag reads 2-way (free), b128-aligned

template <int AM, int BN, int WR, int WC>
__global__ __launch_bounds__(WR * WC * 64, 1) void gemm_mfma_f64(
    const float* __restrict__ A,    // [M,K] row-major
    const float* __restrict__ W,    // [N,K] row-major (C = A @ W^T + bias)
    const float* __restrict__ bias, // [N]
    float* __restrict__ C,          // [M,N]
    int N, int K)
{
    constexpr int TM = WR * AM * 16;
    constexpr int TN = WC * BN * 16;
    constexpr int NTHR = WR * WC * 64;
    constexpr int IA = TM * (KT / 4);   // float4 stage items for A
    constexpr int IW = TN * (KT / 4);
    constexpr int LA = (IA + NTHR - 1) / NTHR;
    constexpr int LW = (IW + NTHR - 1) / NTHR;

    __shared__ float As[TM * LDSS];
    __shared__ float Ws[TN * LDSS];

    const int tid = threadIdx.x;
    const int wid = tid >> 6;
    const int wr  = wid / WC;
    const int wc  = wid % WC;
    const int l15 = tid & 15;          // lane & 15
    const int lk  = (tid >> 4) & 3;    // lane's k-slot within the wave
    const int row0 = blockIdx.y * TM;
    const int col0 = blockIdx.x * TN;

    float4 ra[LA], rw[LW];

    auto loadA = [&](int k0) {
#pragma unroll
        for (int i = 0; i < LA; ++i) {
            int idx = i * NTHR + tid;
            if ((IA % NTHR) == 0 || idx < IA) {
                int r = idx >> 3, k4 = idx & 7;
                ra[i] = *reinterpret_cast<const float4*>(
                    A + (size_t)(row0 + r) * K + k0 + k4 * 4);
            }
        }
    };
    auto loadW = [&](int k0) {
#pragma unroll
        for (int i = 0; i < LW; ++i) {
            int idx = i * NTHR + tid;
            if ((IW % NTHR) == 0 || idx < IW) {
                int r = idx >> 3, k4 = idx & 7;
                rw[i] = *reinterpret_cast<const float4*>(
                    W + (size_t)(col0 + r) * K + k0 + k4 * 4);
            }
        }
    };
    auto storeA = [&]() {
#pragma unroll
        for (int i = 0; i < LA; ++i) {
            int idx = i * NTHR + tid;
            if ((IA % NTHR) == 0 || idx < IA) {
                int r = idx >> 3, k4 = idx & 7;
                *reinterpret_cast<float4*>(&As[r * LDSS + k4 * 4]) = ra[i];
            }
        }
    };
    auto storeW = [&]() {
#pragma unroll
        for (int i = 0; i < LW; ++i) {
            int idx = i * NTHR + tid;
            if ((IW % NTHR) == 0 || idx < IW) {
                int r = idx >> 3, k4 = idx & 7;
                *reinterpret_cast<float4*>(&Ws[r * LDSS + k4 * 4]) = rw[i];
            }
        }
    };

    // Fragment base pointers: lane reads elem [row][k] = [base + l15][ks + lk]
    const float* aP[AM];
    const float* wP[BN];
#pragma unroll
    for (int am = 0; am < AM; ++am)
        aP[am] = &As[(wr * AM * 16 + am * 16 + l15) * LDSS + lk];
#pragma unroll
    for (int bn = 0; bn < BN; ++bn)
        wP[bn] = &Ws[(wc * BN * 16 + bn * 16 + l15) * LDSS + lk];

    f64x4 acc[AM][BN] = {};
    const int NT = K / KT;

    loadA(0);
    loadW(0);

    for (int kt = 0; kt < NT; ++kt) {
        __syncthreads();          // previous compute done; LDS reusable
        storeA();
        storeW();
        __syncthreads();          // tile ready
        if (kt + 1 < NT) {        // prefetch next tile into regs (overlaps MFMA)
            loadA((kt + 1) * KT);
            loadW((kt + 1) * KT);
        }
#pragma unroll
        for (int ks = 0; ks < KT; ks += 4) {
            double a[AM], b[BN];
#pragma unroll
            for (int am = 0; am < AM; ++am) a[am] = (double)aP[am][ks];
#pragma unroll
            for (int bn = 0; bn < BN; ++bn) b[bn] = (double)wP[bn][ks];
#pragma unroll
            for (int am = 0; am < AM; ++am)
#pragma unroll
                for (int bn = 0; bn < BN; ++bn)
                    acc[am][bn] = __builtin_amdgcn_mfma_f64_16x16x4f64(
                        a[am], b[bn], acc[am][bn], 0, 0, 0);
        }
    }

    // ---- C/D layout probe (layout-agnostic epilogue) ----
    // A[m][k] = m (every lane supplies (lane&15); A lane-map m=lane&15,k=lane>>4),
    // B = 1  -> D[m][n] = 4m. Likewise B[k][n]=n, A=1 -> D[m][n] = 4n.
    const f64x4 z = {0.0, 0.0, 0.0, 0.0};
    f64x4 pr = __builtin_amdgcn_mfma_f64_16x16x4f64((double)l15, 1.0, z, 0, 0, 0);
    f64x4 pc = __builtin_amdgcn_mfma_f64_16x16x4f64(1.0, (double)l15, z, 0, 0, 0);
    int rowp[4], colp[4];
#pragma unroll
    for (int i = 0; i < 4; ++i) {
        rowp[i] = ((int)pr[i]) >> 2;
        colp[i] = ((int)pc[i]) >> 2;
    }

    // Epilogue through probed map; bias added in f64.
#pragma unroll
    for (int bn = 0; bn < BN; ++bn) {
        const int cbase = col0 + wc * BN * 16 + bn * 16;
#pragma unroll
        for (int am = 0; am < AM; ++am) {
            const int rbase = row0 + wr * AM * 16 + am * 16;
#pragma unroll
            for (int i = 0; i < 4; ++i) {
                const int cg = cbase + colp[i];
                C[(size_t)(rbase + rowp[i]) * N + cg] =
                    (float)(acc[am][bn][i] + (double)bias[cg]);
            }
        }
    }
}

// mem0(inf) = cur0 + 0.9*[cur0 > 1]; cur0 in lo half (n4 float4s), write hi half.
__global__ __launch_bounds__(256) void lif0_kernel(float4* __restrict__ a1, int n4)
{
    int i = blockIdx.x * 256 + threadIdx.x;
    if (i < n4) {
        float4 c = a1[i], o;
        o.x = c.x + ((c.x > 1.0f) ? 0.9f : 0.0f);
        o.y = c.y + ((c.y > 1.0f) ? 0.9f : 0.0f);
        o.z = c.z + ((c.z > 1.0f) ? 0.9f : 0.0f);
        o.w = c.w + ((c.w > 1.0f) ? 0.9f : 0.0f);
        a1[n4 + i] = o;
    }
}

// From cur1(0), cur1(inf) build mem1(0), mem1(1), mem1(inf).
__global__ __launch_bounds__(256) void lif1_kernel(const float4* __restrict__ c1,
                                                   float4* __restrict__ a2, int n4)
{
    int i = blockIdx.x * 256 + threadIdx.x;
    if (i < n4) {
        float4 c0 = c1[i], ci = c1[n4 + i];
        float4 m0 = c0, m1, mi;
        m1.x = ci.x + ((m0.x > 1.0f) ? 0.9f : 0.0f);
        m1.y = ci.y + ((m0.y > 1.0f) ? 0.9f : 0.0f);
        m1.z = ci.z + ((m0.z > 1.0f) ? 0.9f : 0.0f);
        m1.w = ci.w + ((m0.w > 1.0f) ? 0.9f : 0.0f);
        mi.x = ci.x + ((m1.x > 1.0f) ? 0.9f : 0.0f);
        mi.y = ci.y + ((m1.y > 1.0f) ? 0.9f : 0.0f);
        mi.z = ci.z + ((m1.z > 1.0f) ? 0.9f : 0.0f);
        mi.w = ci.w + ((m1.w > 1.0f) ? 0.9f : 0.0f);
        a2[i] = m0;
        a2[n4 + i] = m1;
        a2[2 * n4 + i] = mi;
    }
}

// Final layer + broadcast; grid.y covers 4 time-slices each (t = 4*y .. 4*y+3).
__global__ __launch_bounds__(256) void lif2_bcast(const float4* __restrict__ c2,
                                                  float4* __restrict__ out, int n4)
{
    int i = blockIdx.x * 256 + threadIdx.x;
    if (i >= n4) return;
    float4 c0 = c2[i], c1 = c2[n4 + i], ci = c2[2 * n4 + i];
    float4 m0 = c0, m1, m2, m3;
    m1.x = c1.x + ((m0.x > 1.0f) ? 0.9f : 0.0f);
    m1.y = c1.y + ((m0.y > 1.0f) ? 0.9f : 0.0f);
    m1.z = c1.z + ((m0.z > 1.0f) ? 0.9f : 0.0f);
    m1.w = c1.w + ((m0.w > 1.0f) ? 0.9f : 0.0f);
    m2.x = ci.x + ((m1.x > 1.0f) ? 0.9f : 0.0f);
    m2.y = ci.y + ((m1.y > 1.0f) ? 0.9f : 0.0f);
    m2.z = ci.z + ((m1.z > 1.0f) ? 0.9f : 0.0f);
    m2.w = ci.w + ((m1.w > 1.0f) ? 0.9f : 0.0f);
    m3.x = ci.x + ((m2.x > 1.0f) ? 0.9f : 0.0f);
    m3.y = ci.y + ((m2.y > 1.0f) ? 0.9f : 0.0f);
    m3.z = ci.z + ((m2.z > 1.0f) ? 0.9f : 0.0f);
    m3.w = ci.w + ((m2.w > 1.0f) ? 0.9f : 0.0f);
    int t0 = blockIdx.y * 4;
#pragma unroll
    for (int j = 0; j < 4; ++j) {
        int t = t0 + j;
        float4 v = (t == 0) ? m0 : (t == 1) ? m1 : (t == 2) ? m2 : m3;
        out[(size_t)t * n4 + i] = v;
    }
}

extern "C" void kernel_launch(void* const* d_in, const int* in_sizes, int n_in,
                              void* d_out, int out_size, void* d_ws, size_t ws_size,
                              hipStream_t stream)
{
    const float* x  = (const float*)d_in[0];  // [256,1024]
    const float* W0 = (const float*)d_in[1];  // [2048,1024]
    const float* b0 = (const float*)d_in[2];  // [2048]
    const float* W1 = (const float*)d_in[3];  // [2048,2048]
    const float* b1 = (const float*)d_in[4];  // [2048]
    const float* W2 = (const float*)d_in[5];  // [1024,2048]
    const float* b2 = (const float*)d_in[6];  // [1024]
    float* out = (float*)d_out;
    float* ws  = (float*)d_ws;

    const int B = 256, H = 2048, DOUT = 1024, DIN = 1024;
    const int nBH4 = B * H / 4;      // 131072 float4
    const int nBO4 = B * DOUT / 4;   // 65536 float4

    // ws layout (floats): A1 [512,2048] @0 ; C1 [512,2048] @1048576 ;
    // A2 [768,2048] @2097152 ; C2 [768,1024] reuses A1's slot (A1 dead by then).
    float* A1 = ws;
    float* C1 = ws + 1048576;
    float* A2 = ws + 2097152;
    float* C2 = ws;

    dim3 blk(256);

    // GEMM0: cur0 = x @ W0^T + b0. Tile 32x64 (AM=1,BN=2,WR=2,WC=2): grid 32x8=256.
    gemm_mfma_f64<1, 2, 2, 2><<<dim3(H / 64, B / 32), blk, 0, stream>>>(x, W0, b0, A1, H, DIN);
    // mem0(inf) -> rows 256..511 of A1
    lif0_kernel<<<dim3(nBH4 / 256), blk, 0, stream>>>((float4*)A1, nBH4);
    // GEMM1: tile 64x64 (2,2,2,2): grid 32x8 = 256.
    gemm_mfma_f64<2, 2, 2, 2><<<dim3(H / 64, (2 * B) / 64), blk, 0, stream>>>(A1, W1, b1, C1, H, H);
    // mem1(0), mem1(1), mem1(inf)
    lif1_kernel<<<dim3(nBH4 / 256), blk, 0, stream>>>((const float4*)C1, (float4*)A2, nBH4);
    // GEMM2: tile 48x64 (AM=3,BN=1,WR=1,WC=4): grid 16x16 = 256.
    gemm_mfma_f64<3, 1, 1, 4><<<dim3(DOUT / 64, (3 * B) / 48), blk, 0, stream>>>(A2, W2, b2, C2, DOUT, H);
    // layer-2 LIF + output broadcast, 2D grid for full write BW (t = 4*y + j)
    lif2_bcast<<<dim3(nBO4 / 256, 25), blk, 0, stream>>>((const float4*)C2, (float4*)out, nBO4);
}

// Round 5
// 285.695 us; speedup vs baseline: 1.7392x; 1.3403x over previous
//
#include <hip/hip_runtime.h>

// SNN with "swapped outputs" bug: stored state = spike (binary), forwarded
// value = membrane. reset = (spk_prev > 1) == 0 always -> mem = cur + 0.9*spk_prev.
// Constant input -> spike patterns fixate: mem0 const t>=1, mem1 t>=2, out t>=3.
// GEMM0 (256x2048,K=1024); GEMM1 over {mem0(0),mem0(inf)} (M=512,K=2048);
// GEMM2 over {mem1(0),mem1(1),mem1(inf)} (M=768,N=1024,K=2048); broadcast t>=3.
//
// Round-4 lesson: f64 MFMA is a 78.6TF pipe and latency-bound at 1 block/CU
// (268us GEMM1, MfmaUtil 4%). Round 5: bf16 MFMA GEMM (2.5PF pipe) + f64
// fixup of borderline elements (|mem-1|<0.04 or |mem-0.1|<0.04 -> exact f64
// recompute, wave-cooperative). bf16 dot error ~1.5e-3 RMS << 0.04, so
// non-fixed values are safe for both output threshold (0.041) and decisions.
// W bf16 copies live in d_out scratch (overwritten by the final broadcast).

typedef unsigned short ushort_t;
typedef __attribute__((ext_vector_type(8))) short bf16x8;
typedef __attribute__((ext_vector_type(4))) float f32x4;

#define GKT 64
#define GLD (GKT + 8)   // 72-short row stride: 144B, 16B-aligned, 2-way frag reads
#define DELTA 0.04f

__device__ inline ushort_t f2bf(float f) {       // RNE f32 -> bf16
    unsigned u = __float_as_uint(f);
    u += 0x7FFFu + ((u >> 16) & 1u);
    return (ushort_t)(u >> 16);
}
__device__ inline float4 ld4(const float* p) { return *reinterpret_cast<const float4*>(p); }

// ---------------- bf16 GEMM: C = A @ W^T + bias, tile 64x64, 4 waves ----------------
__global__ __launch_bounds__(256, 1) void gemm_bf16(
    const ushort_t* __restrict__ A,   // [M,K] bf16
    const ushort_t* __restrict__ W,   // [N,K] bf16
    const float* __restrict__ bias,   // [N]
    float* __restrict__ C,            // [M,N] f32
    int N, int K)
{
    __shared__ ushort_t As[64 * GLD];
    __shared__ ushort_t Ws[64 * GLD];

    const int tid  = threadIdx.x;
    const int row0 = blockIdx.y * 64;
    const int col0 = blockIdx.x * 64;
    const int itr  = tid >> 3;          // staging row 0..31 (item0), +32 (item1)
    const int itk  = (tid & 7) * 8;     // k-chunk of 8 bf16

    const ushort_t* Ap = A + (size_t)(row0 + itr) * K + itk;
    const ushort_t* Wp = W + (size_t)(col0 + itr) * K + itk;
    const size_t r32 = (size_t)32 * K;

    uint4 pa0, pa1, pw0, pw1;
    auto load = [&](int k0) {
        pa0 = *reinterpret_cast<const uint4*>(Ap + k0);
        pa1 = *reinterpret_cast<const uint4*>(Ap + r32 + k0);
        pw0 = *reinterpret_cast<const uint4*>(Wp + k0);
        pw1 = *reinterpret_cast<const uint4*>(Wp + r32 + k0);
    };
    const int s0 = itr * GLD + itk, s1 = s0 + 32 * GLD;
    auto store = [&]() {
        *reinterpret_cast<uint4*>(&As[s0]) = pa0;
        *reinterpret_cast<uint4*>(&As[s1]) = pa1;
        *reinterpret_cast<uint4*>(&Ws[s0]) = pw0;
        *reinterpret_cast<uint4*>(&Ws[s1]) = pw1;
    };

    // wave (wr,wc) owns 32x32; lane frags per m89-verified layouts
    const int lane = tid & 63;
    const int l15  = lane & 15;
    const int kh   = lane >> 4;         // 0..3
    const int wid  = tid >> 6;
    const int wr   = wid >> 1, wc = wid & 1;

    const ushort_t* aB[2];
    const ushort_t* bB[2];
#pragma unroll
    for (int i = 0; i < 2; ++i) {
        aB[i] = &As[(wr * 32 + i * 16 + l15) * GLD + kh * 8];
        bB[i] = &Ws[(wc * 32 + i * 16 + l15) * GLD + kh * 8];
    }

    f32x4 acc[2][2] = {};
    const int NT = K / GKT;

    load(0);
    for (int kt = 0; kt < NT; ++kt) {
        __syncthreads();
        store();
        __syncthreads();
        if (kt + 1 < NT) load((kt + 1) * GKT);
#pragma unroll
        for (int ks = 0; ks < GKT; ks += 32) {
            bf16x8 a0 = *reinterpret_cast<const bf16x8*>(aB[0] + ks);
            bf16x8 a1 = *reinterpret_cast<const bf16x8*>(aB[1] + ks);
            bf16x8 b0 = *reinterpret_cast<const bf16x8*>(bB[0] + ks);
            bf16x8 b1 = *reinterpret_cast<const bf16x8*>(bB[1] + ks);
            acc[0][0] = __builtin_amdgcn_mfma_f32_16x16x32_bf16(a0, b0, acc[0][0], 0, 0, 0);
            acc[0][1] = __builtin_amdgcn_mfma_f32_16x16x32_bf16(a0, b1, acc[0][1], 0, 0, 0);
            acc[1][0] = __builtin_amdgcn_mfma_f32_16x16x32_bf16(a1, b0, acc[1][0], 0, 0, 0);
            acc[1][1] = __builtin_amdgcn_mfma_f32_16x16x32_bf16(a1, b1, acc[1][1], 0, 0, 0);
        }
    }

    // C/D layout (m89): col = lane&15, row = (lane>>4)*4 + reg
#pragma unroll
    for (int bn = 0; bn < 2; ++bn) {
        const int col = col0 + wc * 32 + bn * 16 + l15;
        const float bv = bias[col];
#pragma unroll
        for (int am = 0; am < 2; ++am) {
            const int rb = row0 + wr * 32 + am * 16 + kh * 4;
#pragma unroll
            for (int i = 0; i < 4; ++i)
                C[(size_t)(rb + i) * N + col] = acc[am][bn][i] + bv;
        }
    }
}

// ---------------- f32 -> bf16 conversion (vectorized) ----------------
__global__ __launch_bounds__(256) void cvt_bf16(const float4* __restrict__ src,
                                                ushort4* __restrict__ dst, int n4)
{
    int i = blockIdx.x * 256 + threadIdx.x;
    if (i < n4) {
        float4 v = src[i];
        ushort4 o;
        o.x = f2bf(v.x); o.y = f2bf(v.y); o.z = f2bf(v.z); o.w = f2bf(v.w);
        dst[i] = o;
    }
}

// ---------------- borderline f64 fixup (wave-cooperative) ----------------
// MODE 0: A row = P (x).  MODE 1: A1 recon from C0.  MODE 2: A2 recon from C1.
template <int MODE>
__global__ __launch_bounds__(256) void fixup_kernel(
    float* __restrict__ C, const float* __restrict__ P,
    const float* __restrict__ Wf, const float* __restrict__ bias,
    int logN, int K)
{
    const int idx  = blockIdx.x * 256 + threadIdx.x;
    const int lane = threadIdx.x & 63;
    const int r = idx >> logN;
    const int c = idx & ((1 << logN) - 1);
    const float v = C[idx];
    const bool bad = (fabsf(v - 1.0f) < DELTA) || (fabsf(v - 0.1f) < DELTA);
    unsigned long long m = __ballot(bad);
    while (m) {
        const int src = (int)__ffsll(m) - 1;
        m &= m - 1;
        const int rr = __shfl(r, src);
        const int cc = __shfl(c, src);
        const float* wrow = Wf + (size_t)cc * K;
        double p = 0.0;
        for (int k = lane * 4; k < K; k += 256) {
            const float4 w4 = ld4(wrow + k);
            float4 a4;
            if (MODE == 0) {
                a4 = ld4(P + (size_t)rr * K + k);
            } else if (MODE == 1) {
                if (rr < 256) a4 = ld4(P + (size_t)rr * K + k);
                else {
                    float4 c0 = ld4(P + (size_t)(rr - 256) * K + k);
                    a4.x = c0.x + ((c0.x > 1.0f) ? 0.9f : 0.0f);
                    a4.y = c0.y + ((c0.y > 1.0f) ? 0.9f : 0.0f);
                    a4.z = c0.z + ((c0.z > 1.0f) ? 0.9f : 0.0f);
                    a4.w = c0.w + ((c0.w > 1.0f) ? 0.9f : 0.0f);
                }
            } else {
                const int i0 = rr & 255, pl = rr >> 8;
                float4 c0 = ld4(P + (size_t)i0 * K + k);
                if (pl == 0) a4 = c0;
                else {
                    float4 ci = ld4(P + (size_t)(i0 + 256) * K + k);
                    float4 m1;
                    m1.x = ci.x + ((c0.x > 1.0f) ? 0.9f : 0.0f);
                    m1.y = ci.y + ((c0.y > 1.0f) ? 0.9f : 0.0f);
                    m1.z = ci.z + ((c0.z > 1.0f) ? 0.9f : 0.0f);
                    m1.w = ci.w + ((c0.w > 1.0f) ? 0.9f : 0.0f);
                    if (pl == 1) a4 = m1;
                    else {
                        a4.x = ci.x + ((m1.x > 1.0f) ? 0.9f : 0.0f);
                        a4.y = ci.y + ((m1.y > 1.0f) ? 0.9f : 0.0f);
                        a4.z = ci.z + ((m1.z > 1.0f) ? 0.9f : 0.0f);
                        a4.w = ci.w + ((m1.w > 1.0f) ? 0.9f : 0.0f);
                    }
                }
            }
            p = fma((double)a4.x, (double)w4.x, p);
            p = fma((double)a4.y, (double)w4.y, p);
            p = fma((double)a4.z, (double)w4.z, p);
            p = fma((double)a4.w, (double)w4.w, p);
        }
#pragma unroll
        for (int off = 32; off; off >>= 1) p += __shfl_down(p, off);
        const double tot = __shfl(p, 0);
        if (lane == src) C[idx] = (float)(tot + (double)bias[cc]);
    }
}

// ---------------- LIF kernels (f32 exact; also emit bf16 A for next GEMM) ----------------
__global__ __launch_bounds__(256) void lif0_kernel(const float4* __restrict__ C0,
                                                   ushort4* __restrict__ A1b, int n4)
{
    int i = blockIdx.x * 256 + threadIdx.x;
    if (i < n4) {
        float4 cv = C0[i];
        ushort4 p0, p1;
        p0.x = f2bf(cv.x); p0.y = f2bf(cv.y); p0.z = f2bf(cv.z); p0.w = f2bf(cv.w);
        float4 mi;
        mi.x = cv.x + ((cv.x > 1.0f) ? 0.9f : 0.0f);
        mi.y = cv.y + ((cv.y > 1.0f) ? 0.9f : 0.0f);
        mi.z = cv.z + ((cv.z > 1.0f) ? 0.9f : 0.0f);
        mi.w = cv.w + ((cv.w > 1.0f) ? 0.9f : 0.0f);
        p1.x = f2bf(mi.x); p1.y = f2bf(mi.y); p1.z = f2bf(mi.z); p1.w = f2bf(mi.w);
        A1b[i] = p0; A1b[n4 + i] = p1;
    }
}

__global__ __launch_bounds__(256) void lif1_kernel(const float4* __restrict__ C1,
                                                   ushort4* __restrict__ A2b, int n4)
{
    int i = blockIdx.x * 256 + threadIdx.x;
    if (i < n4) {
        float4 c0 = C1[i], ci = C1[n4 + i];
        float4 m1, m2;
        m1.x = ci.x + ((c0.x > 1.0f) ? 0.9f : 0.0f);
        m1.y = ci.y + ((c0.y > 1.0f) ? 0.9f : 0.0f);
        m1.z = ci.z + ((c0.z > 1.0f) ? 0.9f : 0.0f);
        m1.w = ci.w + ((c0.w > 1.0f) ? 0.9f : 0.0f);
        m2.x = ci.x + ((m1.x > 1.0f) ? 0.9f : 0.0f);
        m2.y = ci.y + ((m1.y > 1.0f) ? 0.9f : 0.0f);
        m2.z = ci.z + ((m1.z > 1.0f) ? 0.9f : 0.0f);
        m2.w = ci.w + ((m1.w > 1.0f) ? 0.9f : 0.0f);
        ushort4 p0, p1, p2;
        p0.x = f2bf(c0.x); p0.y = f2bf(c0.y); p0.z = f2bf(c0.z); p0.w = f2bf(c0.w);
        p1.x = f2bf(m1.x); p1.y = f2bf(m1.y); p1.z = f2bf(m1.z); p1.w = f2bf(m1.w);
        p2.x = f2bf(m2.x); p2.y = f2bf(m2.y); p2.z = f2bf(m2.z); p2.w = f2bf(m2.w);
        A2b[i] = p0; A2b[n4 + i] = p1; A2b[2 * n4 + i] = p2;
    }
}

// Final layer + broadcast; grid.y covers 4 time-slices each.
__global__ __launch_bounds__(256) void lif2_bcast(const float4* __restrict__ c2,
                                                  float4* __restrict__ out, int n4)
{
    int i = blockIdx.x * 256 + threadIdx.x;
    if (i >= n4) return;
    float4 c0 = c2[i], c1 = c2[n4 + i], ci = c2[2 * n4 + i];
    float4 m0 = c0, m1, m2, m3;
    m1.x = c1.x + ((m0.x > 1.0f) ? 0.9f : 0.0f);
    m1.y = c1.y + ((m0.y > 1.0f) ? 0.9f : 0.0f);
    m1.z = c1.z + ((m0.z > 1.0f) ? 0.9f : 0.0f);
    m1.w = c1.w + ((m0.w > 1.0f) ? 0.9f : 0.0f);
    m2.x = ci.x + ((m1.x > 1.0f) ? 0.9f : 0.0f);
    m2.y = ci.y + ((m1.y > 1.0f) ? 0.9f : 0.0f);
    m2.z = ci.z + ((m1.z > 1.0f) ? 0.9f : 0.0f);
    m2.w = ci.w + ((m1.w > 1.0f) ? 0.9f : 0.0f);
    m3.x = ci.x + ((m2.x > 1.0f) ? 0.9f : 0.0f);
    m3.y = ci.y + ((m2.y > 1.0f) ? 0.9f : 0.0f);
    m3.z = ci.z + ((m2.z > 1.0f) ? 0.9f : 0.0f);
    m3.w = ci.w + ((m2.w > 1.0f) ? 0.9f : 0.0f);
    int t0 = blockIdx.y * 4;
#pragma unroll
    for (int j = 0; j < 4; ++j) {
        int t = t0 + j;
        float4 v = (t == 0) ? m0 : (t == 1) ? m1 : (t == 2) ? m2 : m3;
        out[(size_t)t * n4 + i] = v;
    }
}

extern "C" void kernel_launch(void* const* d_in, const int* in_sizes, int n_in,
                              void* d_out, int out_size, void* d_ws, size_t ws_size,
                              hipStream_t stream)
{
    const float* x  = (const float*)d_in[0];  // [256,1024]
    const float* W0 = (const float*)d_in[1];  // [2048,1024]
    const float* b0 = (const float*)d_in[2];
    const float* W1 = (const float*)d_in[3];  // [2048,2048]
    const float* b1 = (const float*)d_in[4];
    const float* W2 = (const float*)d_in[5];  // [1024,2048]
    const float* b2 = (const float*)d_in[6];
    float* out = (float*)d_out;
    float* ws  = (float*)d_ws;

    // ws (floats): C0 @0 (512K) | C1 @512K (1M) | C2 @1.5M (768K) |
    //              xb @2359296 | A1b @2490368 | A2b @3014656  (bf16 in float slots)
    float*    C0  = ws;
    float*    C1  = ws + 524288;
    float*    C2  = ws + 1572864;
    ushort_t* xb  = (ushort_t*)(ws + 2359296);
    ushort_t* A1b = (ushort_t*)(ws + 2490368);
    ushort_t* A2b = (ushort_t*)(ws + 3014656);
    // bf16 W copies live in d_out scratch (fully overwritten by lif2_bcast at the end)
    ushort_t* Wb0 = (ushort_t*)(out);              // 2M bf16
    ushort_t* Wb1 = (ushort_t*)(out + 1048576);    // 4M bf16
    ushort_t* Wb2 = (ushort_t*)(out + 3145728);    // 2M bf16

    dim3 blk(256);

    cvt_bf16<<<dim3(256),  blk, 0, stream>>>((const float4*)x,  (ushort4*)xb,  65536);
    cvt_bf16<<<dim3(2048), blk, 0, stream>>>((const float4*)W0, (ushort4*)Wb0, 524288);
    cvt_bf16<<<dim3(4096), blk, 0, stream>>>((const float4*)W1, (ushort4*)Wb1, 1048576);
    cvt_bf16<<<dim3(2048), blk, 0, stream>>>((const float4*)W2, (ushort4*)Wb2, 524288);

    // GEMM0: cur0 = x @ W0^T + b0  [256,2048]
    gemm_bf16<<<dim3(32, 4), blk, 0, stream>>>(xb, Wb0, b0, C0, 2048, 1024);
    fixup_kernel<0><<<dim3(2048), blk, 0, stream>>>(C0, x, W0, b0, 11, 1024);
    lif0_kernel<<<dim3(512), blk, 0, stream>>>((const float4*)C0, (ushort4*)A1b, 131072);

    // GEMM1: [cur1(0); cur1(inf)] [512,2048]
    gemm_bf16<<<dim3(32, 8), blk, 0, stream>>>(A1b, Wb1, b1, C1, 2048, 2048);
    fixup_kernel<1><<<dim3(4096), blk, 0, stream>>>(C1, C0, W1, b1, 11, 2048);
    lif1_kernel<<<dim3(512), blk, 0, stream>>>((const float4*)C1, (ushort4*)A2b, 131072);

    // GEMM2: 3 layer-2 currents [768,1024]
    gemm_bf16<<<dim3(16, 12), blk, 0, stream>>>(A2b, Wb2, b2, C2, 1024, 2048);
    fixup_kernel<2><<<dim3(3072), blk, 0, stream>>>(C2, C1, W2, b2, 10, 2048);

    // layer-2 LIF + output broadcast (overwrites all of d_out incl. W scratch)
    lif2_bcast<<<dim3(256, 25), blk, 0, stream>>>((const float4*)C2, (float4*)out, 65536);
}